// Round 4
// baseline (372.142 us; speedup 1.0000x reference)
//
#include <hip/hip_runtime.h>

// B=16, NQ=NK=784, D_MODEL=512, H=8, DK=DV=64
#define SZX ((size_t)12544 * 512)   // elements of one [B*784, 512] matrix
#define WSEG ((size_t)262144)       // one 512x512 weight

typedef __attribute__((ext_vector_type(8))) short short8;
typedef __attribute__((ext_vector_type(4))) short short4s;
typedef __attribute__((ext_vector_type(4))) float floatx4;

typedef const __attribute__((address_space(1))) void* gas_cvp;
typedef __attribute__((address_space(3))) void* las_vp;

__device__ __forceinline__ void gl_lds16(const void* g, void* l) {
    __builtin_amdgcn_global_load_lds((gas_cvp)g, (las_vp)l, 16, 0, 0);
}

__device__ __forceinline__ unsigned short f2bf(float f) {
    unsigned int u = __float_as_uint(f);
    u += 0x7fffu + ((u >> 16) & 1u);   // RNE
    return (unsigned short)(u >> 16);
}

__device__ __forceinline__ short8 lds_read8(const unsigned short* p) {
    // p is 8B-aligned (not 16B) — two b64 reads
    short4s a = *(const short4s*)p;
    short4s b = *(const short4s*)(p + 4);
    return __builtin_shufflevector(a, b, 0, 1, 2, 3, 4, 5, 6, 7);
}

#define MFMA16(a, b, c) __builtin_amdgcn_mfma_f32_16x16x32_bf16(a, b, c, 0, 0, 0)

// ---------------- f32 -> bf16 convert, 3 tensors in one dispatch ------------------
__global__ void cvt3(const float* __restrict__ q, const float* __restrict__ k,
                     const float* __restrict__ v,
                     unsigned short* __restrict__ xq, unsigned short* __restrict__ xk,
                     unsigned short* __restrict__ xv, int which) {
    int sel = blockIdx.y + which;
    const float* in = sel == 0 ? q : sel == 1 ? k : v;
    unsigned short* out = sel == 0 ? xq : sel == 1 ? xk : xv;
    size_t i = ((size_t)blockIdx.x * blockDim.x + threadIdx.x) * 4;
    float4 vv = *(const float4*)(in + i);
    ushort4 o = make_ushort4(f2bf(vv.x), f2bf(vv.y), f2bf(vv.z), f2bf(vv.w));
    *(ushort4*)(out + i) = o;
}

// ---------------- weight transpose + convert: Wt[o][i] = bf16(W[i][o]) ------------
__global__ void transpose_cvt(const float* __restrict__ W0, const float* __restrict__ W1,
                              const float* __restrict__ W2, const float* __restrict__ W3,
                              unsigned short* __restrict__ out) {
    __shared__ float tile[32][33];
    const float* W = blockIdx.z == 0 ? W0 : blockIdx.z == 1 ? W1 : blockIdx.z == 2 ? W2 : W3;
    unsigned short* O = out + (size_t)blockIdx.z * WSEG;
    int x = blockIdx.x * 32 + threadIdx.x;
    int y0 = blockIdx.y * 32;
    for (int k = threadIdx.y; k < 32; k += 8)
        tile[k][threadIdx.x] = W[(size_t)(y0 + k) * 512 + x];
    __syncthreads();
    int xo = blockIdx.y * 32 + threadIdx.x;
    int yo0 = blockIdx.x * 32;
    for (int k = threadIdx.y; k < 32; k += 8)
        O[(size_t)(yo0 + k) * 512 + xo] = f2bf(tile[threadIdx.x][k]);
}

// ---------------- merged QKV projection GEMM (128x128 tiles) ----------------------
// z=0: Qb[row][512] = Xq @ Wtq^T + bq        (tm=bx over M=12544, tn=by over N=512)
// z=1: Kb[row][512] = Xk @ Wtk^T + bk
// z=2: Vt[(b*8+h)*64+d][n] — computed swapped: A=Wtv (M=512 out-ch), B=Xv (N=12544)
__global__ __launch_bounds__(256) void gemm_qkv(
    const unsigned short* __restrict__ Xq, const unsigned short* __restrict__ Xk,
    const unsigned short* __restrict__ Xv, const unsigned short* __restrict__ Wt,
    const float* __restrict__ bq, const float* __restrict__ bk, const float* __restrict__ bv,
    unsigned short* __restrict__ Qb, unsigned short* __restrict__ Kb,
    unsigned short* __restrict__ Vtb, int zoff)
{
    __shared__ unsigned short Als[128 * 32];
    __shared__ unsigned short Bls[128 * 32];
    int z = blockIdx.z + zoff;
    const unsigned short* X = z == 0 ? Xq : z == 1 ? Xk : Xv;
    const unsigned short* Wz = Wt + (size_t)z * WSEG;
    const float* bias = z == 0 ? bq : z == 1 ? bk : bv;

    int tid = threadIdx.x;
    int lane = tid & 63, wave = tid >> 6;
    int wm = wave & 1, wn = wave >> 1;
    int c16 = lane & 15, g = lane >> 4;
    int tm, tn;
    const unsigned short *Abase, *Bbase;
    if (z < 2) { tm = blockIdx.x; tn = blockIdx.y; Abase = X + (size_t)tm * 128 * 512; Bbase = Wz + (size_t)tn * 128 * 512; }
    else       { tm = blockIdx.y; tn = blockIdx.x; Abase = Wz + (size_t)tm * 128 * 512; Bbase = X + (size_t)tn * 128 * 512; }

    floatx4 acc[4][4];
#pragma unroll
    for (int i = 0; i < 4; i++)
#pragma unroll
        for (int j = 0; j < 4; j++) acc[i][j] = (floatx4){0.f, 0.f, 0.f, 0.f};

    for (int kb = 0; kb < 16; ++kb) {
        int k0 = kb * 32;
#pragma unroll
        for (int rep = 0; rep < 2; ++rep) {
            int slot = rep * 256 + tid;
            int row = slot >> 2, kp = slot & 3;
            gl_lds16(Abase + (size_t)row * 512 + k0 + kp * 8, &Als[slot * 8]);
            gl_lds16(Bbase + (size_t)row * 512 + k0 + kp * 8, &Bls[slot * 8]);
        }
        __syncthreads();
        short8 af[4], bfr[4];
#pragma unroll
        for (int i = 0; i < 4; i++)
            af[i] = *(const short8*)&Als[(wm * 64 + i * 16 + c16) * 32 + g * 8];
#pragma unroll
        for (int j = 0; j < 4; j++)
            bfr[j] = *(const short8*)&Bls[(wn * 64 + j * 16 + c16) * 32 + g * 8];
#pragma unroll
        for (int i = 0; i < 4; i++)
#pragma unroll
            for (int j = 0; j < 4; j++)
                acc[i][j] = MFMA16(af[i], bfr[j], acc[i][j]);
        __syncthreads();
    }

#pragma unroll
    for (int j = 0; j < 4; j++) {
        int n = tn * 128 + wn * 64 + j * 16 + c16;
        int bi = n / 784, nn = n - bi * 784;         // z==2 only
        float bvn = (z < 2) ? bias[n] : 0.f;
#pragma unroll
        for (int i = 0; i < 4; i++) {
#pragma unroll
            for (int r4 = 0; r4 < 4; r4++) {
                int m = tm * 128 + wm * 64 + i * 16 + g * 4 + r4;
                float v = acc[i][j][r4] + ((z < 2) ? bvn : bias[m]);
                if (z == 0)      Qb[(size_t)m * 512 + n] = f2bf(v);
                else if (z == 1) Kb[(size_t)m * 512 + n] = f2bf(v);
                else {
                    int h = m >> 6, d = m & 63;
                    Vtb[(((size_t)bi * 8 + h) * 64 + d) * 784 + nn] = f2bf(v);
                }
            }
        }
    }
}

// ---------------- output projection, swapped (64x128 tiles): out[b][c][q] f32 -----
// A = Wto [512 out][512 in]; B = ctx [12544][512]
__global__ __launch_bounds__(256) void gemm_out(
    const unsigned short* __restrict__ Wto, const unsigned short* __restrict__ ctx,
    const float* __restrict__ bo, float* __restrict__ out)
{
    __shared__ unsigned short Als[64 * 32];
    __shared__ unsigned short Bls[128 * 32];
    int tid = threadIdx.x;
    int lane = tid & 63, wn = tid >> 6;
    int c16 = lane & 15, g = lane >> 4;
    int tm = blockIdx.x, tn = blockIdx.y;

    const unsigned short* Abase = Wto + (size_t)tm * 64 * 512;
    const unsigned short* Bbase = ctx + (size_t)tn * 128 * 512;

    floatx4 acc[4][2];
#pragma unroll
    for (int i = 0; i < 4; i++)
#pragma unroll
        for (int j = 0; j < 2; j++) acc[i][j] = (floatx4){0.f, 0.f, 0.f, 0.f};

    for (int kb = 0; kb < 16; ++kb) {
        int k0 = kb * 32;
        {
            int row = tid >> 2, kp = tid & 3;
            gl_lds16(Abase + (size_t)row * 512 + k0 + kp * 8, &Als[tid * 8]);
        }
#pragma unroll
        for (int rep = 0; rep < 2; ++rep) {
            int slot = rep * 256 + tid;
            int row = slot >> 2, kp = slot & 3;
            gl_lds16(Bbase + (size_t)row * 512 + k0 + kp * 8, &Bls[slot * 8]);
        }
        __syncthreads();
        short8 af[4], bfr[2];
#pragma unroll
        for (int i = 0; i < 4; i++)
            af[i] = *(const short8*)&Als[(i * 16 + c16) * 32 + g * 8];
#pragma unroll
        for (int j = 0; j < 2; j++)
            bfr[j] = *(const short8*)&Bls[(wn * 32 + j * 16 + c16) * 32 + g * 8];
#pragma unroll
        for (int i = 0; i < 4; i++)
#pragma unroll
            for (int j = 0; j < 2; j++)
                acc[i][j] = MFMA16(af[i], bfr[j], acc[i][j]);
        __syncthreads();
    }

#pragma unroll
    for (int j = 0; j < 2; j++) {
        int n = tn * 128 + wn * 32 + j * 16 + c16;
        int bi = n / 784, q = n - bi * 784;
#pragma unroll
        for (int i = 0; i < 4; i++) {
#pragma unroll
            for (int r4 = 0; r4 < 4; r4++) {
                int m = tm * 64 + i * 16 + g * 4 + r4;
                out[((size_t)bi * 512 + m) * 784 + q] = acc[i][j][r4] + bo[m];
            }
        }
    }
}

// ---------------- fused attention, no-max softmax (bounded logits) ----------------
// v4: v3 (swapped QK, float4 corr, packed P-writes) with two changes:
//   1. ALL s_setprio removed — v1/v2/v3 (133/122/122us) vs v0 (97us) shared only
//      setprio; suspected priority-thrash across 12 unsynced waves/CU (cf. m190).
//   2. corr double-buffered in registers (T14 done right): ccA/ccB statically
//      named (rule #20 — no runtime-indexed reg arrays), loop unrolled by 2.
//      Prefetch for it+1 issues before PV, so PV + next QK (~32 MFMA + softmax
//      VALU) cover the ~900cy cold-HBM latency. +32 VGPR, no launch_bounds
//      min-arg (R2 lesson). Spill tripwire: WRITE_SIZE must stay 12544.
// block = 256 = 4 waves = 4 heads; grid (16 batches, 25 q-tiles, 2 head-halves)
__global__ __launch_bounds__(256) void attn_kernel(
    const unsigned short* __restrict__ Qb,
    const unsigned short* __restrict__ Kb,
    const unsigned short* __restrict__ Vtb,
    const float* __restrict__ corr,
    unsigned short* __restrict__ ctx)
{
    __shared__ unsigned short Plds[2][4][2][16][68];   // [parity][wave][u][query(16)][key(64)+pad4]
    int b = blockIdx.x, qt = blockIdx.y, hh = blockIdx.z;
    int tid = threadIdx.x;
    int lane = tid & 63, w = tid >> 6;
    int h = hh * 4 + w;
    int c16 = lane & 15, g = lane >> 4;
    int q0 = qt * 32;

    short8 aq[2][2];
#pragma unroll
    for (int u = 0; u < 2; ++u) {
        int row = q0 + u * 16 + c16; row = row < 784 ? row : 783;
        const unsigned short* qp = Qb + (size_t)(b * 784 + row) * 512 + h * 64 + g * 8;
        aq[u][0] = *(const short8*)qp;
        aq[u][1] = *(const short8*)(qp + 32);
    }

    floatx4 o[2][4];
    float l[2];
#pragma unroll
    for (int u = 0; u < 2; ++u) {
        l[u] = 0.f;
#pragma unroll
        for (int nt = 0; nt < 4; nt++) o[u][nt] = (floatx4){0.f, 0.f, 0.f, 0.f};
    }

    const float* corrb = corr + (size_t)b * 784 * 784;
    // per-u corr row base (query row for this lane = q0 + u*16 + c16)
    size_t crow[2];
#pragma unroll
    for (int u = 0; u < 2; ++u) {
        int qr = q0 + u * 16 + c16; qr = qr < 784 ? qr : 783;
        crow[u] = (size_t)qr * 784;
    }

    const unsigned short* Vh = Vtb + ((size_t)(b * 8 + h)) * 64 * 784;
    const unsigned short* Kh = Kb + (size_t)b * 784 * 512 + h * 64;

    // corr register double-buffers (statically named — no dynamic indexing)
    float4 ccA[2][4], ccB[2][4];

    auto corr_load = [&](float4 (&dst)[2][4], int it) {
#pragma unroll
        for (int u = 0; u < 2; ++u)
#pragma unroll
            for (int t = 0; t < 4; ++t) {
                int kc = it * 64 + t * 16 + g * 4;
                kc = kc < 780 ? kc : 780;   // clamp keeps reads in-row (invalid quads masked)
                dst[u][t] = *(const float4*)(corrb + crow[u] + kc);
            }
    };

    // one full iteration: consume cin's corr, prefetch it+1 into cnx before PV
    auto body = [&](int it, float4 (&cin)[2][4], float4 (&cnx)[2][4]) {
        int k0 = it * 64;

        // QK^T swapped: s[u][t] = S[key = k0+t*16+g*4+r][query = q0+u*16+c16]
        floatx4 s[2][4];
#pragma unroll
        for (int t = 0; t < 4; ++t) {
            int key = k0 + t * 16 + c16; key = key < 784 ? key : 783;
            const unsigned short* kp = Kh + (size_t)key * 512 + g * 8;
            short8 k0f = *(const short8*)kp;
            short8 k1f = *(const short8*)(kp + 32);
#pragma unroll
            for (int u = 0; u < 2; ++u) {
                floatx4 zz = (floatx4){0.f, 0.f, 0.f, 0.f};
                zz = MFMA16(k0f, aq[u][0], zz);     // operands swapped vs v0
                zz = MFMA16(k1f, aq[u][1], zz);
                s[u][t] = zz;
            }
        }

        // p = exp(s/8 + corr); pack 4 keys -> one b64 LDS write
#pragma unroll
        for (int u = 0; u < 2; ++u)
#pragma unroll
            for (int t = 0; t < 4; ++t) {
                int kb2 = k0 + t * 16 + g * 4;
                const float* cp = (const float*)&cin[u][t];
                float pvv[4];
#pragma unroll
                for (int r = 0; r < 4; ++r) {
                    float sv = fmaf(s[u][t][r], 0.125f, cp[r]);
                    pvv[r] = (kb2 + r < 784) ? __expf(sv) : 0.f;
                    l[u] += pvv[r];
                }
                unsigned int w0 = (unsigned)f2bf(pvv[0]) | ((unsigned)f2bf(pvv[1]) << 16);
                unsigned int w1 = (unsigned)f2bf(pvv[2]) | ((unsigned)f2bf(pvv[3]) << 16);
                *(uint2*)&Plds[it & 1][w][u][c16][t * 16 + g * 4] = make_uint2(w0, w1);
            }

        // prefetch next iteration's corr (cin now dead; covered by PV + next QK)
        if (it < 12) corr_load(cnx, it + 1);

        // P·V  (A = P[query=c16][keys g*8..], B = V[d][keys])
#pragma unroll
        for (int u = 0; u < 2; ++u) {
            const unsigned short* pr = &Plds[it & 1][w][u][c16][0];
            short8 pa0 = lds_read8(pr + g * 8);
            short8 pa1 = lds_read8(pr + 32 + g * 8);
#pragma unroll
            for (int nt = 0; nt < 4; ++nt) {
                int d = nt * 16 + c16;
                const unsigned short* vp = Vh + (size_t)d * 784 + k0 + g * 8;
                short8 v0 = *(const short8*)vp;
                short8 v1 = *(const short8*)(vp + 32);
                o[u][nt] = MFMA16(pa0, v0, o[u][nt]);
                o[u][nt] = MFMA16(pa1, v1, o[u][nt]);
            }
        }
    };

    corr_load(ccA, 0);
    for (int ip = 0; ip < 7; ++ip) {
        int it0 = ip * 2;
        body(it0, ccA, ccB);            // even iter: consume A, prefetch into B
        if (it0 + 1 < 13)
            body(it0 + 1, ccB, ccA);    // odd iter: consume B, prefetch into A
    }

    // l[u] at lane (g,c16) = partial sum (this lane's keys) for query c16.
    // Reduce across the 4 g-groups, then invert.
    float linv[2];
#pragma unroll
    for (int u = 0; u < 2; ++u) {
        float lv = l[u];
        lv += __shfl_xor(lv, 16);
        lv += __shfl_xor(lv, 32);
        linv[u] = 1.0f / lv;
    }
    // Store: o[u][nt][r] is (query row = q0+u*16+g*4+r, d = nt*16+c16).
    // 1/l for query qq lives at lanes with c16==qq; fetch from lane qq.
#pragma unroll
    for (int u = 0; u < 2; ++u)
#pragma unroll
        for (int r = 0; r < 4; ++r) {
            int row = q0 + u * 16 + g * 4 + r;
            float li = __shfl(linv[u], g * 4 + r);
            if (row < 784) {
#pragma unroll
                for (int nt = 0; nt < 4; ++nt)
                    ctx[(size_t)(b * 784 + row) * 512 + h * 64 + nt * 16 + c16] =
                        f2bf(o[u][nt][r] * li);
            }
        }
}

extern "C" void kernel_launch(void* const* d_in, const int* in_sizes, int n_in,
                              void* d_out, int out_size, void* d_ws, size_t ws_size,
                              hipStream_t stream) {
    (void)in_sizes; (void)n_in; (void)out_size;
    const float* queries = (const float*)d_in[0];
    const float* keys    = (const float*)d_in[1];
    const float* values  = (const float*)d_in[2];
    const float* corr    = (const float*)d_in[3];
    const float* Wq = (const float*)d_in[4];
    const float* bq = (const float*)d_in[5];
    const float* Wk = (const float*)d_in[6];
    const float* bk = (const float*)d_in[7];
    const float* Wv = (const float*)d_in[8];
    const float* bv = (const float*)d_in[9];
    const float* Wo = (const float*)d_in[10];
    const float* bo = (const float*)d_in[11];

    size_t need = (6 * SZX + 4 * WSEG) * 2;
    if (ws_size >= need) {
        unsigned short* Xq  = (unsigned short*)d_ws;     // later reused as ctx
        unsigned short* Xk  = Xq + SZX;
        unsigned short* Xv  = Xk + SZX;
        unsigned short* Qb  = Xv + SZX;
        unsigned short* Kb  = Qb + SZX;
        unsigned short* Vtb = Kb + SZX;
        unsigned short* Wt  = Vtb + SZX;

        transpose_cvt<<<dim3(16, 16, 4), dim3(32, 8), 0, stream>>>(Wq, Wk, Wv, Wo, Wt);
        cvt3<<<dim3(6272, 3), 256, 0, stream>>>(queries, keys, values, Xq, Xk, Xv, 0);
        gemm_qkv<<<dim3(98, 4, 3), 256, 0, stream>>>(Xq, Xk, Xv, Wt, bq, bk, bv, Qb, Kb, Vtb, 0);
        attn_kernel<<<dim3(16, 25, 2), 256, 0, stream>>>(Qb, Kb, Vtb, corr, Xq);
        gemm_out<<<dim3(8, 98), 256, 0, stream>>>(Wt + 3 * WSEG, Xq, bo, (float*)d_out);
    } else {
        // sequential fallback with a single shared X buffer (53.5 MB)
        unsigned short* X   = (unsigned short*)d_ws;
        unsigned short* Qb  = X + SZX;
        unsigned short* Kb  = Qb + SZX;
        unsigned short* Vtb = Kb + SZX;
        unsigned short* Wt  = Vtb + SZX;

        transpose_cvt<<<dim3(16, 16, 4), dim3(32, 8), 0, stream>>>(Wq, Wk, Wv, Wo, Wt);
        for (int z = 0; z < 3; ++z) {
            cvt3<<<dim3(6272, 1), 256, 0, stream>>>(queries, keys, values, X, X, X, z);
            gemm_qkv<<<dim3(98, 4, 1), 256, 0, stream>>>(X, X, X, Wt, bq, bk, bv, Qb, Kb, Vtb, z);
        }
        attn_kernel<<<dim3(16, 25, 2), 256, 0, stream>>>(Qb, Kb, Vtb, corr, X);
        gemm_out<<<dim3(8, 98), 256, 0, stream>>>(Wt + 3 * WSEG, X, bo, (float*)d_out);
    }
}

// Round 6
// 333.168 us; speedup vs baseline: 1.1170x; 1.1170x over previous
//
#include <hip/hip_runtime.h>

// B=16, NQ=NK=784, D_MODEL=512, H=8, DK=DV=64
#define SZX ((size_t)12544 * 512)   // elements of one [B*784, 512] matrix
#define WSEG ((size_t)262144)       // one 512x512 weight

typedef __attribute__((ext_vector_type(8))) short short8;
typedef __attribute__((ext_vector_type(4))) short short4s;
typedef __attribute__((ext_vector_type(4))) float floatx4;

typedef const __attribute__((address_space(1))) void* gas_cvp;
typedef __attribute__((address_space(3))) void* las_vp;

__device__ __forceinline__ void gl_lds16(const void* g, void* l) {
    __builtin_amdgcn_global_load_lds((gas_cvp)g, (las_vp)l, 16, 0, 0);
}

__device__ __forceinline__ unsigned short f2bf(float f) {
    unsigned int u = __float_as_uint(f);
    u += 0x7fffu + ((u >> 16) & 1u);   // RNE
    return (unsigned short)(u >> 16);
}

__device__ __forceinline__ short8 lds_read8(const unsigned short* p) {
    // p is 8B-aligned (not 16B) — two b64 reads
    short4s a = *(const short4s*)p;
    short4s b = *(const short4s*)(p + 4);
    return __builtin_shufflevector(a, b, 0, 1, 2, 3, 4, 5, 6, 7);
}

#define MFMA16(a, b, c) __builtin_amdgcn_mfma_f32_16x16x32_bf16(a, b, c, 0, 0, 0)

// ---------------- f32 -> bf16 convert, 3 tensors in one dispatch ------------------
__global__ void cvt3(const float* __restrict__ q, const float* __restrict__ k,
                     const float* __restrict__ v,
                     unsigned short* __restrict__ xq, unsigned short* __restrict__ xk,
                     unsigned short* __restrict__ xv, int which) {
    int sel = blockIdx.y + which;
    const float* in = sel == 0 ? q : sel == 1 ? k : v;
    unsigned short* out = sel == 0 ? xq : sel == 1 ? xk : xv;
    size_t i = ((size_t)blockIdx.x * blockDim.x + threadIdx.x) * 4;
    float4 vv = *(const float4*)(in + i);
    ushort4 o = make_ushort4(f2bf(vv.x), f2bf(vv.y), f2bf(vv.z), f2bf(vv.w));
    *(ushort4*)(out + i) = o;
}

// ---------------- weight transpose + convert: Wt[o][i] = bf16(W[i][o]) ------------
__global__ void transpose_cvt(const float* __restrict__ W0, const float* __restrict__ W1,
                              const float* __restrict__ W2, const float* __restrict__ W3,
                              unsigned short* __restrict__ out) {
    __shared__ float tile[32][33];
    const float* W = blockIdx.z == 0 ? W0 : blockIdx.z == 1 ? W1 : blockIdx.z == 2 ? W2 : W3;
    unsigned short* O = out + (size_t)blockIdx.z * WSEG;
    int x = blockIdx.x * 32 + threadIdx.x;
    int y0 = blockIdx.y * 32;
    for (int k = threadIdx.y; k < 32; k += 8)
        tile[k][threadIdx.x] = W[(size_t)(y0 + k) * 512 + x];
    __syncthreads();
    int xo = blockIdx.y * 32 + threadIdx.x;
    int yo0 = blockIdx.x * 32;
    for (int k = threadIdx.y; k < 32; k += 8)
        O[(size_t)(yo0 + k) * 512 + xo] = f2bf(tile[threadIdx.x][k]);
}

// ---------------- merged QKV projection GEMM (128x128 tiles) ----------------------
// z=0: Qb[row][512] = Xq @ Wtq^T + bq        (tm=bx over M=12544, tn=by over N=512)
// z=1: Kb[row][512] = Xk @ Wtk^T + bk
// z=2: Vt[(b*8+h)*64+d][n] — computed swapped: A=Wtv (M=512 out-ch), B=Xv (N=12544)
__global__ __launch_bounds__(256) void gemm_qkv(
    const unsigned short* __restrict__ Xq, const unsigned short* __restrict__ Xk,
    const unsigned short* __restrict__ Xv, const unsigned short* __restrict__ Wt,
    const float* __restrict__ bq, const float* __restrict__ bk, const float* __restrict__ bv,
    unsigned short* __restrict__ Qb, unsigned short* __restrict__ Kb,
    unsigned short* __restrict__ Vtb, int zoff)
{
    __shared__ unsigned short Als[128 * 32];
    __shared__ unsigned short Bls[128 * 32];
    int z = blockIdx.z + zoff;
    const unsigned short* X = z == 0 ? Xq : z == 1 ? Xk : Xv;
    const unsigned short* Wz = Wt + (size_t)z * WSEG;
    const float* bias = z == 0 ? bq : z == 1 ? bk : bv;

    int tid = threadIdx.x;
    int lane = tid & 63, wave = tid >> 6;
    int wm = wave & 1, wn = wave >> 1;
    int c16 = lane & 15, g = lane >> 4;
    int tm, tn;
    const unsigned short *Abase, *Bbase;
    if (z < 2) { tm = blockIdx.x; tn = blockIdx.y; Abase = X + (size_t)tm * 128 * 512; Bbase = Wz + (size_t)tn * 128 * 512; }
    else       { tm = blockIdx.y; tn = blockIdx.x; Abase = Wz + (size_t)tm * 128 * 512; Bbase = X + (size_t)tn * 128 * 512; }

    floatx4 acc[4][4];
#pragma unroll
    for (int i = 0; i < 4; i++)
#pragma unroll
        for (int j = 0; j < 4; j++) acc[i][j] = (floatx4){0.f, 0.f, 0.f, 0.f};

    for (int kb = 0; kb < 16; ++kb) {
        int k0 = kb * 32;
#pragma unroll
        for (int rep = 0; rep < 2; ++rep) {
            int slot = rep * 256 + tid;
            int row = slot >> 2, kp = slot & 3;
            gl_lds16(Abase + (size_t)row * 512 + k0 + kp * 8, &Als[slot * 8]);
            gl_lds16(Bbase + (size_t)row * 512 + k0 + kp * 8, &Bls[slot * 8]);
        }
        __syncthreads();
        short8 af[4], bfr[4];
#pragma unroll
        for (int i = 0; i < 4; i++)
            af[i] = *(const short8*)&Als[(wm * 64 + i * 16 + c16) * 32 + g * 8];
#pragma unroll
        for (int j = 0; j < 4; j++)
            bfr[j] = *(const short8*)&Bls[(wn * 64 + j * 16 + c16) * 32 + g * 8];
#pragma unroll
        for (int i = 0; i < 4; i++)
#pragma unroll
            for (int j = 0; j < 4; j++)
                acc[i][j] = MFMA16(af[i], bfr[j], acc[i][j]);
        __syncthreads();
    }

#pragma unroll
    for (int j = 0; j < 4; j++) {
        int n = tn * 128 + wn * 64 + j * 16 + c16;
        int bi = n / 784, nn = n - bi * 784;         // z==2 only
        float bvn = (z < 2) ? bias[n] : 0.f;
#pragma unroll
        for (int i = 0; i < 4; i++) {
#pragma unroll
            for (int r4 = 0; r4 < 4; r4++) {
                int m = tm * 128 + wm * 64 + i * 16 + g * 4 + r4;
                float v = acc[i][j][r4] + ((z < 2) ? bvn : bias[m]);
                if (z == 0)      Qb[(size_t)m * 512 + n] = f2bf(v);
                else if (z == 1) Kb[(size_t)m * 512 + n] = f2bf(v);
                else {
                    int h = m >> 6, d = m & 63;
                    Vtb[(((size_t)bi * 8 + h) * 64 + d) * 784 + nn] = f2bf(v);
                }
            }
        }
    }
}

// ---------------- output projection, swapped (64x128 tiles): out[b][c][q] f32 -----
// A = Wto [512 out][512 in]; B = ctx [12544][512]
__global__ __launch_bounds__(256) void gemm_out(
    const unsigned short* __restrict__ Wto, const unsigned short* __restrict__ ctx,
    const float* __restrict__ bo, float* __restrict__ out)
{
    __shared__ unsigned short Als[64 * 32];
    __shared__ unsigned short Bls[128 * 32];
    int tid = threadIdx.x;
    int lane = tid & 63, wn = tid >> 6;
    int c16 = lane & 15, g = lane >> 4;
    int tm = blockIdx.x, tn = blockIdx.y;

    const unsigned short* Abase = Wto + (size_t)tm * 64 * 512;
    const unsigned short* Bbase = ctx + (size_t)tn * 128 * 512;

    floatx4 acc[4][2];
#pragma unroll
    for (int i = 0; i < 4; i++)
#pragma unroll
        for (int j = 0; j < 2; j++) acc[i][j] = (floatx4){0.f, 0.f, 0.f, 0.f};

    for (int kb = 0; kb < 16; ++kb) {
        int k0 = kb * 32;
        {
            int row = tid >> 2, kp = tid & 3;
            gl_lds16(Abase + (size_t)row * 512 + k0 + kp * 8, &Als[tid * 8]);
        }
#pragma unroll
        for (int rep = 0; rep < 2; ++rep) {
            int slot = rep * 256 + tid;
            int row = slot >> 2, kp = slot & 3;
            gl_lds16(Bbase + (size_t)row * 512 + k0 + kp * 8, &Bls[slot * 8]);
        }
        __syncthreads();
        short8 af[4], bfr[2];
#pragma unroll
        for (int i = 0; i < 4; i++)
            af[i] = *(const short8*)&Als[(i * 16 + c16) * 32 + g * 8];
#pragma unroll
        for (int j = 0; j < 2; j++)
            bfr[j] = *(const short8*)&Bls[(wn * 32 + j * 16 + c16) * 32 + g * 8];
#pragma unroll
        for (int i = 0; i < 4; i++)
#pragma unroll
            for (int j = 0; j < 2; j++)
                acc[i][j] = MFMA16(af[i], bfr[j], acc[i][j]);
        __syncthreads();
    }

#pragma unroll
    for (int j = 0; j < 2; j++) {
        int n = tn * 128 + wn * 32 + j * 16 + c16;
        int bi = n / 784, q = n - bi * 784;
#pragma unroll
        for (int i = 0; i < 4; i++) {
#pragma unroll
            for (int r4 = 0; r4 < 4; r4++) {
                int m = tm * 64 + i * 16 + g * 4 + r4;
                out[((size_t)bi * 512 + m) * 784 + q] = acc[i][j][r4] + bo[m];
            }
        }
    }
}

// ---------------- fused attention, no-max softmax (bounded logits) ----------------
// v6 = v5 (corr via async global_load_lds DMA, zero VGPR) with the RACE FIXED:
// explicit `s_waitcnt vmcnt(0)` + sched_barrier(0) before softmax reads Clds.
// (v5 read Clds while the DMA was in flight — global_load_lds raises vmcnt and
// the compiler does not track its LDS-destination aliasing; the GEMMs were only
// safe because __syncthreads() forces the drain.) Also: DMA for it+1 now issues
// right after softmax(it) finishes reading Clds, so PV(it) + QK(it+1) (~32 MFMA
// + K/V loads) cover the ~900cy cold-HBM latency; single Clds buffer is safe by
// program order (reads of it retired before DMA it+1 issues; next reads sit
// behind the vmcnt wait). LDS = 17408 (Plds) + 32768 (Clds) = 50176 -> 3 blk/CU.
// Spill tripwire: WRITE_SIZE must stay 12544.
// block = 256 = 4 waves = 4 heads; grid (16 batches, 25 q-tiles, 2 head-halves)
__global__ __launch_bounds__(256) void attn_kernel(
    const unsigned short* __restrict__ Qb,
    const unsigned short* __restrict__ Kb,
    const unsigned short* __restrict__ Vtb,
    const float* __restrict__ corr,
    unsigned short* __restrict__ ctx)
{
    __shared__ unsigned short Plds[4][2][16][68];   // [wave][u][row][key(64)+pad4]
    __shared__ float Clds[4][32][64];               // [wave][q-row(32)][key(64)]
    int b = blockIdx.x, qt = blockIdx.y, hh = blockIdx.z;
    int tid = threadIdx.x;
    int lane = tid & 63, w = tid >> 6;
    int h = hh * 4 + w;
    int c16 = lane & 15, g = lane >> 4;
    int q0 = qt * 32;

    short8 aq[2][2];
#pragma unroll
    for (int u = 0; u < 2; ++u) {
        int row = q0 + u * 16 + c16; row = row < 784 ? row : 783;
        const unsigned short* qp = Qb + (size_t)(b * 784 + row) * 512 + h * 64 + g * 8;
        aq[u][0] = *(const short8*)qp;
        aq[u][1] = *(const short8*)(qp + 32);
    }

    floatx4 o[2][4];
    float l[2][4];
#pragma unroll
    for (int u = 0; u < 2; ++u)
#pragma unroll
        for (int nt = 0; nt < 4; nt++) { o[u][nt] = (floatx4){0.f, 0.f, 0.f, 0.f}; l[u][nt] = 0.f; }

    const float* corrb = corr + (size_t)b * 784 * 784;

    // per-lane source geometry for the corr DMA: lane = jr*16 + jc covers
    // (row j*4+jr, 16B chunk jc) — LDS dest is exactly base + lane*16 (linear).
    int jr = lane >> 4;          // row within 4-row group
    int jc = lane & 15;          // 16B column chunk
    // clamped global rows for this lane's 8 DMA instructions
    size_t crow_dma[8];
#pragma unroll
    for (int j = 0; j < 8; ++j) {
        int row = q0 + j * 4 + jr; row = row < 784 ? row : 783;
        crow_dma[j] = (size_t)row * 784;
    }

    const unsigned short* Vh = Vtb + ((size_t)(b * 8 + h)) * 64 * 784;
    const unsigned short* Kh = Kb + (size_t)b * 784 * 512 + h * 64;

    // async corr DMA for k-tile `it`: 8 x 1KB -> Clds[w][0..31][0..63]
    auto corr_dma = [&](int it) {
        int kstart = it * 64 + jc * 4;
        kstart = kstart < 780 ? kstart : 780;   // stay in-row; invalid keys masked later
#pragma unroll
        for (int j = 0; j < 8; ++j)
            gl_lds16(corrb + crow_dma[j] + kstart, &Clds[w][j * 4 + jr][jc * 4]);
    };

    corr_dma(0);   // prologue: only it=0's DMA is covered by QK alone

    for (int it = 0; it < 13; ++it) {
        int k0 = it * 64;

        // QK^T: s[u][t] over 64 keys (plus K loads — covers in-flight corr DMA)
        floatx4 s[2][4];
#pragma unroll
        for (int t = 0; t < 4; ++t) {
            int key = k0 + t * 16 + c16; key = key < 784 ? key : 783;
            const unsigned short* kp = Kh + (size_t)key * 512 + g * 8;
            short8 k0f = *(const short8*)kp;
            short8 k1f = *(const short8*)(kp + 32);
#pragma unroll
            for (int u = 0; u < 2; ++u) {
                floatx4 zz = (floatx4){0.f, 0.f, 0.f, 0.f};
                zz = MFMA16(aq[u][0], k0f, zz);
                zz = MFMA16(aq[u][1], k1f, zz);
                s[u][t] = zz;
            }
        }

        // drain the corr DMA before reading Clds (race fix — the whole v5 bug)
        asm volatile("s_waitcnt vmcnt(0)" ::: "memory");
        __builtin_amdgcn_sched_barrier(0);

        // p = exp(s/8 + corr)  (no max: logits bounded by ~6); corr from LDS
        unsigned short* pbase = &Plds[w][0][0][0];
#pragma unroll
        for (int u = 0; u < 2; ++u)
#pragma unroll
            for (int t = 0; t < 4; ++t) {
                int key = k0 + t * 16 + c16;
                bool valid = key < 784;
#pragma unroll
                for (int r = 0; r < 4; ++r) {
                    float cv = Clds[w][u * 16 + g * 4 + r][t * 16 + c16];
                    float sv = fmaf(s[u][t][r], 0.125f, cv);
                    float pv = valid ? __expf(sv) : 0.f;
                    l[u][r] += pv;
                    pbase[(u * 16 + g * 4 + r) * 68 + t * 16 + c16] = f2bf(pv);
                }
            }

        // issue next k-tile's corr DMA now (Clds reads above have retired);
        // PV below + next QK cover its latency.
        if (it < 12) corr_dma(it + 1);

        // P·V
#pragma unroll
        for (int u = 0; u < 2; ++u) {
            const unsigned short* pr = &Plds[w][u][c16][0];
            short8 pa0 = lds_read8(pr + g * 8);
            short8 pa1 = lds_read8(pr + 32 + g * 8);
#pragma unroll
            for (int nt = 0; nt < 4; ++nt) {
                int d = nt * 16 + c16;
                const unsigned short* vp = Vh + (size_t)d * 784 + k0 + g * 8;
                short8 v0 = *(const short8*)vp;
                short8 v1 = *(const short8*)(vp + 32);
                o[u][nt] = MFMA16(pa0, v0, o[u][nt]);
                o[u][nt] = MFMA16(pa1, v1, o[u][nt]);
            }
        }
    }

    // normalize and store
#pragma unroll
    for (int u = 0; u < 2; ++u)
#pragma unroll
        for (int r = 0; r < 4; ++r) {
            float lv = l[u][r];
            lv += __shfl_xor(lv, 1);
            lv += __shfl_xor(lv, 2);
            lv += __shfl_xor(lv, 4);
            lv += __shfl_xor(lv, 8);
            l[u][r] = 1.0f / lv;
        }
#pragma unroll
    for (int u = 0; u < 2; ++u)
#pragma unroll
        for (int r = 0; r < 4; ++r) {
            int row = q0 + u * 16 + g * 4 + r;
            if (row < 784) {
#pragma unroll
                for (int nt = 0; nt < 4; ++nt)
                    ctx[(size_t)(b * 784 + row) * 512 + h * 64 + nt * 16 + c16] =
                        f2bf(o[u][nt][r] * l[u][r]);
            }
        }
}

extern "C" void kernel_launch(void* const* d_in, const int* in_sizes, int n_in,
                              void* d_out, int out_size, void* d_ws, size_t ws_size,
                              hipStream_t stream) {
    (void)in_sizes; (void)n_in; (void)out_size;
    const float* queries = (const float*)d_in[0];
    const float* keys    = (const float*)d_in[1];
    const float* values  = (const float*)d_in[2];
    const float* corr    = (const float*)d_in[3];
    const float* Wq = (const float*)d_in[4];
    const float* bq = (const float*)d_in[5];
    const float* Wk = (const float*)d_in[6];
    const float* bk = (const float*)d_in[7];
    const float* Wv = (const float*)d_in[8];
    const float* bv = (const float*)d_in[9];
    const float* Wo = (const float*)d_in[10];
    const float* bo = (const float*)d_in[11];

    size_t need = (6 * SZX + 4 * WSEG) * 2;
    if (ws_size >= need) {
        unsigned short* Xq  = (unsigned short*)d_ws;     // later reused as ctx
        unsigned short* Xk  = Xq + SZX;
        unsigned short* Xv  = Xk + SZX;
        unsigned short* Qb  = Xv + SZX;
        unsigned short* Kb  = Qb + SZX;
        unsigned short* Vtb = Kb + SZX;
        unsigned short* Wt  = Vtb + SZX;

        transpose_cvt<<<dim3(16, 16, 4), dim3(32, 8), 0, stream>>>(Wq, Wk, Wv, Wo, Wt);
        cvt3<<<dim3(6272, 3), 256, 0, stream>>>(queries, keys, values, Xq, Xk, Xv, 0);
        gemm_qkv<<<dim3(98, 4, 3), 256, 0, stream>>>(Xq, Xk, Xv, Wt, bq, bk, bv, Qb, Kb, Vtb, 0);
        attn_kernel<<<dim3(16, 25, 2), 256, 0, stream>>>(Qb, Kb, Vtb, corr, Xq);
        gemm_out<<<dim3(8, 98), 256, 0, stream>>>(Wt + 3 * WSEG, Xq, bo, (float*)d_out);
    } else {
        // sequential fallback with a single shared X buffer (53.5 MB)
        unsigned short* X   = (unsigned short*)d_ws;
        unsigned short* Qb  = X + SZX;
        unsigned short* Kb  = Qb + SZX;
        unsigned short* Vtb = Kb + SZX;
        unsigned short* Wt  = Vtb + SZX;

        transpose_cvt<<<dim3(16, 16, 4), dim3(32, 8), 0, stream>>>(Wq, Wk, Wv, Wo, Wt);
        for (int z = 0; z < 3; ++z) {
            cvt3<<<dim3(6272, 1), 256, 0, stream>>>(queries, keys, values, X, X, X, z);
            gemm_qkv<<<dim3(98, 4, 1), 256, 0, stream>>>(X, X, X, Wt, bq, bk, bv, Qb, Kb, Vtb, z);
        }
        attn_kernel<<<dim3(16, 25, 2), 256, 0, stream>>>(Qb, Kb, Vtb, corr, X);
        gemm_out<<<dim3(8, 98), 256, 0, stream>>>(Wt + 3 * WSEG, X, bo, (float*)d_out);
    }
}